// Round 5
// baseline (397.497 us; speedup 1.0000x reference)
//
#include <hip/hip_runtime.h>
#include <stdint.h>

#define B_  4
#define H_  16
#define N_  1024
#define D_  64
#define SS_II 328   // halfs per ii-row of Ss: [ii][j*20 + h], +8 pad
#define A2_G  328   // halfs per g-row of A2s: [g][ii*20 + j], +8 pad

typedef _Float16 half4v __attribute__((ext_vector_type(4)));
typedef _Float16 half8v __attribute__((ext_vector_type(8)));
typedef float    f32x4  __attribute__((ext_vector_type(4)));

// workspace layout (bytes)
#define LBUF_SZ  (B_ * H_ * N_ * 4)                  // 262144
#define VT_OFF   LBUF_SZ
#define VT_SZ    (B_ * H_ * D_ * N_ * 2)             // 8 MB
#define KH_OFF   (VT_OFF + VT_SZ)
#define KH_SZ    (B_ * H_ * N_ * D_ * 2)             // 8 MB
#define WS_NEED  ((size_t)(KH_OFF + KH_SZ))

__device__ __forceinline__ half4v cvt4(f32x4 v) {
    half4v h;
    h[0] = (_Float16)v[0]; h[1] = (_Float16)v[1];
    h[2] = (_Float16)v[2]; h[3] = (_Float16)v[3];
    return h;
}

// per-batch WG id [0,288) -> (i-tile it in [0,64), chunk c of 8 j-tiles)
__device__ __forceinline__ void decode_wg(int wid, int& it, int& c) {
    int kg = 0;
    while (4 * (kg + 1) * (kg + 2) <= wid) ++kg;
    const int u = wid - 4 * kg * (kg + 1), per = kg + 1;
    it = 8 * kg + u / per;
    c  = u % per;
}

// ---------------- prep: V transpose to f16 VT[b,h,d,j] ----------------
__global__ __launch_bounds__(256)
void prep_vt(const float* __restrict__ v, _Float16* __restrict__ VT) {
    __shared__ float T[64 * 67];
    const int t = threadIdx.x;
    const int bh = blockIdx.x >> 4, jb = blockIdx.x & 15, j0 = jb * 64;
    const float* src = v + ((size_t)bh * N_ + j0) * D_;
    #pragma unroll
    for (int m = 0; m < 4; ++m) {
        const int flat = m * 1024 + t * 4;
        const int j = flat >> 6, d0 = flat & 63;
        f32x4 val = *(const f32x4*)(src + flat);
        #pragma unroll
        for (int e = 0; e < 4; ++e) T[j * 67 + d0 + e] = val[e];
    }
    __syncthreads();
    const int d = t >> 2, jq = t & 3;
    half8v a, b2;
    #pragma unroll
    for (int jj = 0; jj < 8; ++jj) a[jj]  = (_Float16)T[(16 * jq + jj) * 67 + d];
    #pragma unroll
    for (int jj = 0; jj < 8; ++jj) b2[jj] = (_Float16)T[(16 * jq + 8 + jj) * 67 + d];
    _Float16* dst = VT + ((size_t)bh * D_ + d) * N_ + j0 + jq * 16;
    *(half8v*)dst = a;
    *(half8v*)(dst + 8) = b2;
}

// ---------------- prep: K to f16 (row-major, same layout) ----------------
__global__ __launch_bounds__(256)
void prep_kh(const float* __restrict__ k, _Float16* __restrict__ Kh) {
    const size_t idx = ((size_t)blockIdx.x * 256 + threadIdx.x) * 8;
    f32x4 a = *(const f32x4*)(k + idx);
    f32x4 b = *(const f32x4*)(k + idx + 4);
    half8v h;
    #pragma unroll
    for (int e = 0; e < 4; ++e) { h[e] = (_Float16)a[e]; h[4 + e] = (_Float16)b[e]; }
    *(half8v*)(Kh + idx) = h;
}

// ---------------- Kernel A: softmax denominators l[b,h,i] ----------------
template<bool WS>
__global__ __launch_bounds__(256, 4)
void attend_lsum(const float* __restrict__ q, const float* __restrict__ k,
                 const _Float16* __restrict__ Kh, const float* __restrict__ Wpre,
                 float* __restrict__ lbuf) {
    __shared__ _Float16 Ss[16 * SS_II];   // 10,496 B

    const int t = threadIdx.x;
    const int b = blockIdx.x / 288;
    int it, c; decode_wg(blockIdx.x % 288, it, c);
    const int i0 = it * 16;
    const int jt0 = c * 8, jt1 = min(c * 8 + 8, it + 1);

    const int lane = t & 63, w = t >> 6;
    const int l16 = lane & 15, lg = lane >> 4;
    const size_t bh0 = (size_t)b * H_;

    const half4v wpre_f = cvt4(*(const f32x4*)(Wpre + l16 * 16 + 4 * lg));

    // Q fragments (scale folded)
    half4v qf[4][4];
    #pragma unroll
    for (int hh = 0; hh < 4; ++hh) {
        const int h = w * 4 + hh;
        const float* qrow = q + ((bh0 + h) * N_ + i0 + l16) * D_;
        #pragma unroll
        for (int kk = 0; kk < 4; ++kk) {
            f32x4 qv = *(const f32x4*)(qrow + kk * 16 + 4 * lg);
            half4v hv;
            #pragma unroll
            for (int e = 0; e < 4; ++e) hv[e] = (_Float16)(qv[e] * 0.125f);
            qf[hh][kk] = hv;
        }
    }

    float lp[4][4];
    #pragma unroll
    for (int ss = 0; ss < 4; ++ss)
        #pragma unroll
        for (int r = 0; r < 4; ++r) lp[ss][r] = 0.f;

    for (int jt = jt0; jt < jt1; ++jt) {
        const int j0 = jt * 16;
        // K fragments (issued together, one wait)
        half4v kf[4][4];
        #pragma unroll
        for (int hh = 0; hh < 4; ++hh) {
            const int h = w * 4 + hh;
            if (WS) {
                const _Float16* krow = Kh + ((bh0 + h) * N_ + j0 + l16) * D_ + 4 * lg;
                #pragma unroll
                for (int kk = 0; kk < 4; ++kk) kf[hh][kk] = *(const half4v*)(krow + kk * 16);
            } else {
                const float* krow = k + ((bh0 + h) * N_ + j0 + l16) * D_ + 4 * lg;
                #pragma unroll
                for (int kk = 0; kk < 4; ++kk) kf[hh][kk] = cvt4(*(const f32x4*)(krow + kk * 16));
            }
        }
        // QK^T -> Ss[ii][j*20 + h]
        #pragma unroll
        for (int hh = 0; hh < 4; ++hh) {
            const int h = w * 4 + hh;
            f32x4 acc = {0.f, 0.f, 0.f, 0.f};
            #pragma unroll
            for (int kk = 0; kk < 4; ++kk)
                acc = __builtin_amdgcn_mfma_f32_16x16x16f16(qf[hh][kk], kf[hh][kk], acc, 0, 0, 0);
            #pragma unroll
            for (int r = 0; r < 4; ++r)
                Ss[(4 * lg + r) * SS_II + l16 * 20 + h] = (_Float16)acc[r];
        }
        __syncthreads();
        // mix1 via MFMA + masked exp accumulate
        #pragma unroll
        for (int ss = 0; ss < 4; ++ss) {
            const int sii = 4 * w + ss;
            half4v sfrag = *(const half4v*)&Ss[sii * SS_II + l16 * 20 + 4 * lg];
            f32x4 z = {0.f, 0.f, 0.f, 0.f};
            f32x4 m1 = __builtin_amdgcn_mfma_f32_16x16x16f16(wpre_f, sfrag, z, 0, 0, 0);
            const bool ok = (jt < it) || (l16 <= sii);
            if (ok) {
                #pragma unroll
                for (int r = 0; r < 4; ++r) lp[ss][r] += __expf(m1[r]);
            }
        }
        __syncthreads();
    }

    #pragma unroll
    for (int ss = 0; ss < 4; ++ss) {
        #pragma unroll
        for (int r = 0; r < 4; ++r) {
            float val = lp[ss][r];
            val += __shfl_xor(val, 1, 64);
            val += __shfl_xor(val, 2, 64);
            val += __shfl_xor(val, 4, 64);
            val += __shfl_xor(val, 8, 64);
            if (l16 == 0)
                atomicAdd(&lbuf[(bh0 + 4 * lg + r) * N_ + i0 + 4 * w + ss], val);
        }
    }
}

// ---------------- Kernel B: output ----------------
template<bool WS>
__global__ __launch_bounds__(256, 2)
void attend_out(const float* __restrict__ q, const float* __restrict__ k,
                const float* __restrict__ v, const _Float16* __restrict__ Kh,
                const _Float16* __restrict__ VT, const float* __restrict__ Wpre,
                const float* __restrict__ Wpost, const float* __restrict__ lbuf,
                float* __restrict__ out) {
    __shared__ _Float16 Ss[16 * SS_II];    // 10,496 B
    __shared__ _Float16 A2s[16 * A2_G];    // 10,496 B

    const int t = threadIdx.x;
    const int b = blockIdx.x / 288;
    int it, c; decode_wg(blockIdx.x % 288, it, c);
    const int i0 = it * 16;
    const int jt0 = c * 8, jt1 = min(c * 8 + 8, it + 1);

    const int lane = t & 63, w = t >> 6;
    const int l16 = lane & 15, lg = lane >> 4;
    const size_t bh0 = (size_t)b * H_;

    const half4v wpre_f  = cvt4(*(const f32x4*)(Wpre  + l16 * 16 + 4 * lg));
    const half4v wpost_f = cvt4(*(const f32x4*)(Wpost + l16 * 16 + 4 * lg));

    // Q fragments (scale folded)
    half4v qf[4][4];
    #pragma unroll
    for (int hh = 0; hh < 4; ++hh) {
        const int h = w * 4 + hh;
        const float* qrow = q + ((bh0 + h) * N_ + i0 + l16) * D_;
        #pragma unroll
        for (int kk = 0; kk < 4; ++kk) {
            f32x4 qv = *(const f32x4*)(qrow + kk * 16 + 4 * lg);
            half4v hv;
            #pragma unroll
            for (int e = 0; e < 4; ++e) hv[e] = (_Float16)(qv[e] * 0.125f);
            qf[hh][kk] = hv;
        }
    }

    // 1/l for softmax head 4lg+r, row 4w+ss
    float lrecip[4][4];
    #pragma unroll
    for (int ss = 0; ss < 4; ++ss)
        #pragma unroll
        for (int r = 0; r < 4; ++r)
            lrecip[ss][r] = 1.0f / lbuf[(bh0 + 4 * lg + r) * N_ + i0 + 4 * w + ss];

    f32x4 oacc[4][4];
    #pragma unroll
    for (int hh = 0; hh < 4; ++hh)
        #pragma unroll
        for (int ds = 0; ds < 4; ++ds)
            oacc[hh][ds] = (f32x4){0.f, 0.f, 0.f, 0.f};

    for (int jt = jt0; jt < jt1; ++jt) {
        const int j0 = jt * 16;
        // K fragments first (QK^T waits on these only) ...
        half4v kf[4][4];
        #pragma unroll
        for (int hh = 0; hh < 4; ++hh) {
            const int h = w * 4 + hh;
            if (WS) {
                const _Float16* krow = Kh + ((bh0 + h) * N_ + j0 + l16) * D_ + 4 * lg;
                #pragma unroll
                for (int kk = 0; kk < 4; ++kk) kf[hh][kk] = *(const half4v*)(krow + kk * 16);
            } else {
                const float* krow = k + ((bh0 + h) * N_ + j0 + l16) * D_ + 4 * lg;
                #pragma unroll
                for (int kk = 0; kk < 4; ++kk) kf[hh][kk] = cvt4(*(const f32x4*)(krow + kk * 16));
            }
        }
        // ... then V^T fragments (stay in flight under QK^T + mix)
        half4v vf[4][4];
        #pragma unroll
        for (int hh = 0; hh < 4; ++hh) {
            const int h = w * 4 + hh;
            #pragma unroll
            for (int ds = 0; ds < 4; ++ds) {
                if (WS) {
                    vf[hh][ds] = *(const half4v*)(VT + ((bh0 + h) * D_ + ds * 16 + l16) * N_ + j0 + 4 * lg);
                } else {
                    f32x4 vv;
                    #pragma unroll
                    for (int e = 0; e < 4; ++e)
                        vv[e] = v[((bh0 + h) * N_ + j0 + 4 * lg + e) * D_ + ds * 16 + l16];
                    vf[hh][ds] = cvt4(vv);
                }
            }
        }
        // QK^T -> Ss[ii][j*20 + h]
        #pragma unroll
        for (int hh = 0; hh < 4; ++hh) {
            const int h = w * 4 + hh;
            f32x4 acc = {0.f, 0.f, 0.f, 0.f};
            #pragma unroll
            for (int kk = 0; kk < 4; ++kk)
                acc = __builtin_amdgcn_mfma_f32_16x16x16f16(qf[hh][kk], kf[hh][kk], acc, 0, 0, 0);
            #pragma unroll
            for (int r = 0; r < 4; ++r)
                Ss[(4 * lg + r) * SS_II + l16 * 20 + h] = (_Float16)acc[r];
        }
        __syncthreads();
        // mix1 -> exp/mask/normalize (in-register) -> mix2 -> A2s[g][ii*20+j]
        #pragma unroll
        for (int ss = 0; ss < 4; ++ss) {
            const int sii = 4 * w + ss;
            half4v sfrag = *(const half4v*)&Ss[sii * SS_II + l16 * 20 + 4 * lg];
            f32x4 z = {0.f, 0.f, 0.f, 0.f};
            f32x4 m1 = __builtin_amdgcn_mfma_f32_16x16x16f16(wpre_f, sfrag, z, 0, 0, 0);
            const bool ok = (jt < it) || (l16 <= sii);
            half4v pfrag;
            #pragma unroll
            for (int r = 0; r < 4; ++r)
                pfrag[r] = (_Float16)(ok ? __expf(m1[r]) * lrecip[ss][r] : 0.f);
            f32x4 m2 = __builtin_amdgcn_mfma_f32_16x16x16f16(wpost_f, pfrag, z, 0, 0, 0);
            #pragma unroll
            for (int r = 0; r < 4; ++r)
                A2s[(4 * lg + r) * A2_G + sii * 20 + l16] = (_Float16)m2[r];
        }
        __syncthreads();
        // PV: O^T[d,i] += V^T[d,j] * A2^T[j,i]
        #pragma unroll
        for (int hh = 0; hh < 4; ++hh) {
            const int h = w * 4 + hh;
            half4v bfrag = *(const half4v*)&A2s[h * A2_G + l16 * 20 + 4 * lg];
            #pragma unroll
            for (int ds = 0; ds < 4; ++ds)
                oacc[hh][ds] = __builtin_amdgcn_mfma_f32_16x16x16f16(vf[hh][ds], bfrag, oacc[hh][ds], 0, 0, 0);
        }
    }

    // accumulate output: O[i0+l16, ds*16+4lg+r] for wave's heads
    #pragma unroll
    for (int hh = 0; hh < 4; ++hh) {
        const int h = w * 4 + hh;
        float* orow = out + ((bh0 + h) * N_ + i0 + l16) * D_;
        #pragma unroll
        for (int ds = 0; ds < 4; ++ds) {
            #pragma unroll
            for (int r = 0; r < 4; ++r)
                atomicAdd(&orow[ds * 16 + 4 * lg + r], oacc[hh][ds][r]);
        }
    }
}

extern "C" void kernel_launch(void* const* d_in, const int* in_sizes, int n_in,
                              void* d_out, int out_size, void* d_ws, size_t ws_size,
                              hipStream_t stream) {
    const float* q     = (const float*)d_in[0];
    const float* k     = (const float*)d_in[1];
    const float* v     = (const float*)d_in[2];
    const float* Wpre  = (const float*)d_in[3];
    const float* Wpost = (const float*)d_in[4];
    float* out  = (float*)d_out;
    float* lbuf = (float*)d_ws;
    _Float16* VT = (_Float16*)((char*)d_ws + VT_OFF);
    _Float16* Kh = (_Float16*)((char*)d_ws + KH_OFF);

    hipMemsetAsync(d_out, 0, (size_t)out_size * sizeof(float), stream);
    hipMemsetAsync(d_ws, 0, LBUF_SZ, stream);

    const bool big = ws_size >= WS_NEED;
    dim3 block(256);
    dim3 grid(B_ * 288);
    if (big) {
        prep_vt<<<dim3(B_ * H_ * (N_ / 64)), block, 0, stream>>>(v, VT);
        prep_kh<<<dim3((B_ * H_ * N_ * D_) / (256 * 8)), block, 0, stream>>>(k, Kh);
        attend_lsum<true><<<grid, block, 0, stream>>>(q, k, Kh, Wpre, lbuf);
        attend_out<true><<<grid, block, 0, stream>>>(q, k, v, Kh, VT, Wpre, Wpost, lbuf, out);
    } else {
        attend_lsum<false><<<grid, block, 0, stream>>>(q, k, Kh, Wpre, lbuf);
        attend_out<false><<<grid, block, 0, stream>>>(q, k, v, Kh, VT, Wpre, Wpost, lbuf, out);
    }
}

// Round 6
// 387.009 us; speedup vs baseline: 1.0271x; 1.0271x over previous
//
#include <hip/hip_runtime.h>
#include <stdint.h>

#define B_  4
#define H_  16
#define N_  1024
#define D_  64
#define SS_R 328   // halfs per i-row of Ss: [i in 0..32)][j*20 + h], +8 pad
#define A2_R 648   // halfs per g-row of A2s: [g][row32*20 + j], +8 pad

typedef _Float16 half4v __attribute__((ext_vector_type(4)));
typedef _Float16 half8v __attribute__((ext_vector_type(8)));
typedef float    f32x4  __attribute__((ext_vector_type(4)));

// workspace layout (bytes)
#define VT_SZ    (B_ * H_ * D_ * N_ * 2)             // 8 MB
#define KH_OFF   VT_SZ
#define KH_SZ    (B_ * H_ * N_ * D_ * 2)             // 8 MB
#define WS_NEED  ((size_t)(KH_OFF + KH_SZ))

__device__ __forceinline__ half4v cvt4(f32x4 v) {
    half4v h;
    h[0] = (_Float16)v[0]; h[1] = (_Float16)v[1];
    h[2] = (_Float16)v[2]; h[3] = (_Float16)v[3];
    return h;
}

// ---------------- prep: V transpose to f16 VT[b,h,d,j] ----------------
__global__ __launch_bounds__(256)
void prep_vt(const float* __restrict__ v, _Float16* __restrict__ VT) {
    __shared__ float T[64 * 67];
    const int t = threadIdx.x;
    const int bh = blockIdx.x >> 4, jb = blockIdx.x & 15, j0 = jb * 64;
    const float* src = v + ((size_t)bh * N_ + j0) * D_;
    #pragma unroll
    for (int m = 0; m < 4; ++m) {
        const int flat = m * 1024 + t * 4;
        const int j = flat >> 6, d0 = flat & 63;
        f32x4 val = *(const f32x4*)(src + flat);
        #pragma unroll
        for (int e = 0; e < 4; ++e) T[j * 67 + d0 + e] = val[e];
    }
    __syncthreads();
    const int d = t >> 2, jq = t & 3;
    half8v a, b2;
    #pragma unroll
    for (int jj = 0; jj < 8; ++jj) a[jj]  = (_Float16)T[(16 * jq + jj) * 67 + d];
    #pragma unroll
    for (int jj = 0; jj < 8; ++jj) b2[jj] = (_Float16)T[(16 * jq + 8 + jj) * 67 + d];
    _Float16* dst = VT + ((size_t)bh * D_ + d) * N_ + j0 + jq * 16;
    *(half8v*)dst = a;
    *(half8v*)(dst + 8) = b2;
}

// ---------------- prep: K to f16 (row-major) ----------------
__global__ __launch_bounds__(256)
void prep_kh(const float* __restrict__ k, _Float16* __restrict__ Kh) {
    const size_t idx = ((size_t)blockIdx.x * 256 + threadIdx.x) * 8;
    f32x4 a = *(const f32x4*)(k + idx);
    f32x4 b = *(const f32x4*)(k + idx + 4);
    half8v h;
    #pragma unroll
    for (int e = 0; e < 4; ++e) { h[e] = (_Float16)a[e]; h[4 + e] = (_Float16)b[e]; }
    *(half8v*)(Kh + idx) = h;
}

// ---------------- fused: mirror-paired strips, two in-kernel sweeps ----------------
template<bool WS>
__global__ __launch_bounds__(512, 2)
void attend_fused(const float* __restrict__ q, const float* __restrict__ k,
                  const float* __restrict__ v, const _Float16* __restrict__ Kh,
                  const _Float16* __restrict__ VT, const float* __restrict__ Wpre,
                  const float* __restrict__ Wpost, float* __restrict__ out) {
    __shared__ _Float16 Ss[32 * SS_R];    // 20,992 B  rows 0-15: strip A, 16-31: strip B
    __shared__ _Float16 A2s[16 * A2_R];   // 20,736 B

    const int t = threadIdx.x;
    const int b = blockIdx.x >> 5;
    const int m = blockIdx.x & 31;
    const int itA = m, itB = 63 - m;
    const int i0A = m * 16, i0B = (63 - m) * 16;

    const int lane = t & 63, w = t >> 6;        // 8 waves
    const int l16 = lane & 15, lg = lane >> 4;
    const int h0 = 2 * w;                        // wave's heads: h0, h0+1
    const size_t bh0 = (size_t)b * H_;

    const half4v wpre_f  = cvt4(*(const f32x4*)(Wpre  + l16 * 16 + 4 * lg));
    const half4v wpost_f = cvt4(*(const f32x4*)(Wpost + l16 * 16 + 4 * lg));

    // Q fragments (scale folded): qf[strip][head][kk]
    half4v qf[2][2][4];
    #pragma unroll
    for (int s = 0; s < 2; ++s) {
        const int i0s = s ? i0B : i0A;
        #pragma unroll
        for (int e = 0; e < 2; ++e) {
            const float* qrow = q + ((bh0 + h0 + e) * N_ + i0s + l16) * D_;
            #pragma unroll
            for (int kk = 0; kk < 4; ++kk) {
                f32x4 qv = *(const f32x4*)(qrow + kk * 16 + 4 * lg);
                half4v hv;
                #pragma unroll
                for (int x = 0; x < 4; ++x) hv[x] = (_Float16)(qv[x] * 0.125f);
                qf[s][e][kk] = hv;
            }
        }
    }

    // =============== sweep 1: softmax denominators (registers only) ===============
    float lp[4][4];
    #pragma unroll
    for (int ss = 0; ss < 4; ++ss)
        #pragma unroll
        for (int r = 0; r < 4; ++r) lp[ss][r] = 0.f;

    for (int jt = 0; jt <= itB; ++jt) {
        const int j0 = jt * 16;
        const bool actA = (jt <= itA);
        // K fragments (shared by both strips)
        half4v kf[2][4];
        #pragma unroll
        for (int e = 0; e < 2; ++e) {
            if (WS) {
                const _Float16* krow = Kh + ((bh0 + h0 + e) * N_ + j0 + l16) * D_ + 4 * lg;
                #pragma unroll
                for (int kk = 0; kk < 4; ++kk) kf[e][kk] = *(const half4v*)(krow + kk * 16);
            } else {
                const float* krow = k + ((bh0 + h0 + e) * N_ + j0 + l16) * D_ + 4 * lg;
                #pragma unroll
                for (int kk = 0; kk < 4; ++kk) kf[e][kk] = cvt4(*(const f32x4*)(krow + kk * 16));
            }
        }
        // QK^T -> Ss  (strip B always, strip A when active)
        #pragma unroll
        for (int s = 0; s < 2; ++s) {
            if (s == 0 && !actA) continue;
            #pragma unroll
            for (int e = 0; e < 2; ++e) {
                f32x4 acc = {0.f, 0.f, 0.f, 0.f};
                #pragma unroll
                for (int kk = 0; kk < 4; ++kk)
                    acc = __builtin_amdgcn_mfma_f32_16x16x16f16(qf[s][e][kk], kf[e][kk], acc, 0, 0, 0);
                #pragma unroll
                for (int r = 0; r < 4; ++r)
                    Ss[(s * 16 + 4 * lg + r) * SS_R + l16 * 20 + h0 + e] = (_Float16)acc[r];
            }
        }
        __syncthreads();
        // mix1 + masked exp accumulate; task = ss*8 + w -> strip = ss>>1, sii = (ss&1)*8 + w
        #pragma unroll
        for (int ss = 0; ss < 4; ++ss) {
            const int strip = ss >> 1;
            if (strip == 0 && !actA) continue;
            const int sii = (ss & 1) * 8 + w;
            const int its = strip ? itB : itA;
            half4v sfrag = *(const half4v*)&Ss[(strip * 16 + sii) * SS_R + l16 * 20 + 4 * lg];
            f32x4 z = {0.f, 0.f, 0.f, 0.f};
            f32x4 m1 = __builtin_amdgcn_mfma_f32_16x16x16f16(wpre_f, sfrag, z, 0, 0, 0);
            if ((jt < its) || (l16 <= sii)) {
                #pragma unroll
                for (int r = 0; r < 4; ++r) lp[ss][r] += __expf(m1[r]);
            }
        }
        __syncthreads();
    }

    // butterfly all-reduce over l16 -> every lane holds its (row, g) denominator
    float lrec[4][4];
    #pragma unroll
    for (int ss = 0; ss < 4; ++ss) {
        #pragma unroll
        for (int r = 0; r < 4; ++r) {
            float val = lp[ss][r];
            val += __shfl_xor(val, 1, 64);
            val += __shfl_xor(val, 2, 64);
            val += __shfl_xor(val, 4, 64);
            val += __shfl_xor(val, 8, 64);
            lrec[ss][r] = 1.0f / val;
        }
    }

    // =============== sweep 2: output ===============
    f32x4 oacc[2][2][4];
    #pragma unroll
    for (int s = 0; s < 2; ++s)
        #pragma unroll
        for (int e = 0; e < 2; ++e)
            #pragma unroll
            for (int ds = 0; ds < 4; ++ds)
                oacc[s][e][ds] = (f32x4){0.f, 0.f, 0.f, 0.f};

    for (int jt = 0; jt <= itB; ++jt) {
        const int j0 = jt * 16;
        const bool actA = (jt <= itA);
        // K fragments, then V^T fragments (V stays in flight under QK^T + mix)
        half4v kf[2][4];
        #pragma unroll
        for (int e = 0; e < 2; ++e) {
            if (WS) {
                const _Float16* krow = Kh + ((bh0 + h0 + e) * N_ + j0 + l16) * D_ + 4 * lg;
                #pragma unroll
                for (int kk = 0; kk < 4; ++kk) kf[e][kk] = *(const half4v*)(krow + kk * 16);
            } else {
                const float* krow = k + ((bh0 + h0 + e) * N_ + j0 + l16) * D_ + 4 * lg;
                #pragma unroll
                for (int kk = 0; kk < 4; ++kk) kf[e][kk] = cvt4(*(const f32x4*)(krow + kk * 16));
            }
        }
        half4v vf[2][4];
        #pragma unroll
        for (int e = 0; e < 2; ++e) {
            #pragma unroll
            for (int ds = 0; ds < 4; ++ds) {
                if (WS) {
                    vf[e][ds] = *(const half4v*)(VT + ((bh0 + h0 + e) * D_ + ds * 16 + l16) * N_ + j0 + 4 * lg);
                } else {
                    f32x4 vv;
                    #pragma unroll
                    for (int x = 0; x < 4; ++x)
                        vv[x] = v[((bh0 + h0 + e) * N_ + j0 + 4 * lg + x) * D_ + ds * 16 + l16];
                    vf[e][ds] = cvt4(vv);
                }
            }
        }
        // QK^T -> Ss
        #pragma unroll
        for (int s = 0; s < 2; ++s) {
            if (s == 0 && !actA) continue;
            #pragma unroll
            for (int e = 0; e < 2; ++e) {
                f32x4 acc = {0.f, 0.f, 0.f, 0.f};
                #pragma unroll
                for (int kk = 0; kk < 4; ++kk)
                    acc = __builtin_amdgcn_mfma_f32_16x16x16f16(qf[s][e][kk], kf[e][kk], acc, 0, 0, 0);
                #pragma unroll
                for (int r = 0; r < 4; ++r)
                    Ss[(s * 16 + 4 * lg + r) * SS_R + l16 * 20 + h0 + e] = (_Float16)acc[r];
            }
        }
        __syncthreads();
        // mix1 -> exp/mask/normalize -> mix2 -> A2s
        #pragma unroll
        for (int ss = 0; ss < 4; ++ss) {
            const int strip = ss >> 1;
            if (strip == 0 && !actA) continue;
            const int sii = (ss & 1) * 8 + w;
            const int its = strip ? itB : itA;
            half4v sfrag = *(const half4v*)&Ss[(strip * 16 + sii) * SS_R + l16 * 20 + 4 * lg];
            f32x4 z = {0.f, 0.f, 0.f, 0.f};
            f32x4 m1 = __builtin_amdgcn_mfma_f32_16x16x16f16(wpre_f, sfrag, z, 0, 0, 0);
            const bool ok = (jt < its) || (l16 <= sii);
            half4v pfrag;
            #pragma unroll
            for (int r = 0; r < 4; ++r)
                pfrag[r] = (_Float16)(ok ? __expf(m1[r]) * lrec[ss][r] : 0.f);
            f32x4 m2 = __builtin_amdgcn_mfma_f32_16x16x16f16(wpost_f, pfrag, z, 0, 0, 0);
            #pragma unroll
            for (int r = 0; r < 4; ++r)
                A2s[(4 * lg + r) * A2_R + (strip * 16 + sii) * 20 + l16] = (_Float16)m2[r];
        }
        __syncthreads();
        // PV: O^T[d,i] += V^T[d,j] * A2^T[j,i]
        #pragma unroll
        for (int s = 0; s < 2; ++s) {
            if (s == 0 && !actA) continue;
            #pragma unroll
            for (int e = 0; e < 2; ++e) {
                half4v bfrag = *(const half4v*)&A2s[(h0 + e) * A2_R + (s * 16 + l16) * 20 + 4 * lg];
                #pragma unroll
                for (int ds = 0; ds < 4; ++ds)
                    oacc[s][e][ds] = __builtin_amdgcn_mfma_f32_16x16x16f16(vf[e][ds], bfrag, oacc[s][e][ds], 0, 0, 0);
            }
        }
        // no barrier: PV reads A2s, next QK^T writes Ss (disjoint); barrier after QK^T protects A2s
    }

    // plain vector stores — WG owns these rows exclusively
    #pragma unroll
    for (int s = 0; s < 2; ++s) {
        const int i0s = s ? i0B : i0A;
        #pragma unroll
        for (int e = 0; e < 2; ++e) {
            float* orow = out + ((bh0 + h0 + e) * N_ + i0s + l16) * D_;
            #pragma unroll
            for (int ds = 0; ds < 4; ++ds)
                *(f32x4*)&orow[ds * 16 + 4 * lg] = oacc[s][e][ds];
        }
    }
}

extern "C" void kernel_launch(void* const* d_in, const int* in_sizes, int n_in,
                              void* d_out, int out_size, void* d_ws, size_t ws_size,
                              hipStream_t stream) {
    const float* q     = (const float*)d_in[0];
    const float* k     = (const float*)d_in[1];
    const float* v     = (const float*)d_in[2];
    const float* Wpre  = (const float*)d_in[3];
    const float* Wpost = (const float*)d_in[4];
    float* out  = (float*)d_out;
    _Float16* VT = (_Float16*)d_ws;
    _Float16* Kh = (_Float16*)((char*)d_ws + KH_OFF);

    const bool big = ws_size >= WS_NEED;
    dim3 grid(B_ * 32);     // 128 balanced mirror-pair WGs
    dim3 block(512);
    if (big) {
        prep_vt<<<dim3(B_ * H_ * (N_ / 64)), dim3(256), 0, stream>>>(v, VT);
        prep_kh<<<dim3((B_ * H_ * N_ * D_) / (256 * 8)), dim3(256), 0, stream>>>(k, Kh);
        attend_fused<true><<<grid, block, 0, stream>>>(q, k, v, Kh, VT, Wpre, Wpost, out);
    } else {
        attend_fused<false><<<grid, block, 0, stream>>>(q, k, v, Kh, VT, Wpre, Wpost, out);
    }
}

// Round 7
// 218.770 us; speedup vs baseline: 1.8170x; 1.7690x over previous
//
#include <hip/hip_runtime.h>
#include <stdint.h>

#define B_  4
#define H_  16
#define N_  1024
#define D_  64
#define SS_R 328   // halfs per i-row of Ss: [i in 0..32)][j*20 + h], +8 pad
#define A2_R 648   // halfs per g-row of A2s: [g][row32*20 + j], +8 pad

typedef _Float16 half4v __attribute__((ext_vector_type(4)));
typedef _Float16 half8v __attribute__((ext_vector_type(8)));
typedef float    f32x4  __attribute__((ext_vector_type(4)));

// workspace layout (bytes)
#define VT_OFF   0
#define VT_SZ    (B_ * H_ * D_ * N_ * 2)             // 8 MB
#define KH_OFF   (VT_OFF + VT_SZ)
#define KH_SZ    (B_ * H_ * N_ * D_ * 2)             // 8 MB
#define LB_OFF   (KH_OFF + KH_SZ)
#define LB_SZ    (B_ * H_ * N_ * 4)                  // 256 KB
#define PT_OFF   (LB_OFF + LB_SZ)
#define PT_SZ    (512 * 32768 * 4)                   // 64 MB partial-out
#define WS_MIN   ((size_t)(KH_OFF + KH_SZ))
#define WS_FULL  ((size_t)PT_OFF + (size_t)PT_SZ)

__device__ __forceinline__ half4v cvt4(f32x4 v) {
    half4v h;
    h[0] = (_Float16)v[0]; h[1] = (_Float16)v[1];
    h[2] = (_Float16)v[2]; h[3] = (_Float16)v[3];
    return h;
}

// ---------------- prep: V transpose to f16 VT[b,h,d,j] ----------------
__global__ __launch_bounds__(256)
void prep_vt(const float* __restrict__ v, _Float16* __restrict__ VT) {
    __shared__ float T[64 * 67];
    const int t = threadIdx.x;
    const int bh = blockIdx.x >> 4, jb = blockIdx.x & 15, j0 = jb * 64;
    const float* src = v + ((size_t)bh * N_ + j0) * D_;
    #pragma unroll
    for (int m = 0; m < 4; ++m) {
        const int flat = m * 1024 + t * 4;
        const int j = flat >> 6, d0 = flat & 63;
        f32x4 val = *(const f32x4*)(src + flat);
        #pragma unroll
        for (int e = 0; e < 4; ++e) T[j * 67 + d0 + e] = val[e];
    }
    __syncthreads();
    const int d = t >> 2, jq = t & 3;
    half8v a, b2;
    #pragma unroll
    for (int jj = 0; jj < 8; ++jj) a[jj]  = (_Float16)T[(16 * jq + jj) * 67 + d];
    #pragma unroll
    for (int jj = 0; jj < 8; ++jj) b2[jj] = (_Float16)T[(16 * jq + 8 + jj) * 67 + d];
    _Float16* dst = VT + ((size_t)bh * D_ + d) * N_ + j0 + jq * 16;
    *(half8v*)dst = a;
    *(half8v*)(dst + 8) = b2;
}

// ---------------- prep: K to f16 (row-major) ----------------
__global__ __launch_bounds__(256)
void prep_kh(const float* __restrict__ k, _Float16* __restrict__ Kh) {
    const size_t idx = ((size_t)blockIdx.x * 256 + threadIdx.x) * 8;
    f32x4 a = *(const f32x4*)(k + idx);
    f32x4 b = *(const f32x4*)(k + idx + 4);
    half8v h;
    #pragma unroll
    for (int e = 0; e < 4; ++e) { h[e] = (_Float16)a[e]; h[4 + e] = (_Float16)b[e]; }
    *(half8v*)(Kh + idx) = h;
}

// decode blockIdx (0..511) -> slot grouped per XCD (consecutive slots same XCD)
__device__ __forceinline__ int xcd_slot(int x) { return (x >> 3) + (x & 7) * 64; }

// ---------------- phase kernel A: softmax denominators (atomic l) ----------------
__global__ __launch_bounds__(512, 2)
void attend_lsum_p(const float* __restrict__ q, const _Float16* __restrict__ Kh,
                   const float* __restrict__ Wpre, float* __restrict__ lbuf) {
    __shared__ _Float16 Ss[32 * SS_R];    // 20,992 B

    const int slot = xcd_slot(blockIdx.x);
    const int b = slot >> 7;
    const int r7 = slot & 127;
    const int m = r7 >> 2, phase = r7 & 3;
    const int itA = m, itB = 63 - m;
    const int i0A = m * 16, i0B = itB * 16;

    const int t = threadIdx.x;
    const int lane = t & 63, w = t >> 6;        // 8 waves
    const int l16 = lane & 15, lg = lane >> 4;
    const int h0 = 2 * w;
    const size_t bh0 = (size_t)b * H_;

    const half4v wpre_f = cvt4(*(const f32x4*)(Wpre + l16 * 16 + 4 * lg));

    half4v qf[2][2][4];
    #pragma unroll
    for (int s = 0; s < 2; ++s) {
        const int i0s = s ? i0B : i0A;
        #pragma unroll
        for (int e = 0; e < 2; ++e) {
            const float* qrow = q + ((bh0 + h0 + e) * N_ + i0s + l16) * D_;
            #pragma unroll
            for (int kk = 0; kk < 4; ++kk) {
                f32x4 qv = *(const f32x4*)(qrow + kk * 16 + 4 * lg);
                half4v hv;
                #pragma unroll
                for (int x = 0; x < 4; ++x) hv[x] = (_Float16)(qv[x] * 0.125f);
                qf[s][e][kk] = hv;
            }
        }
    }

    float lp[4][4];
    #pragma unroll
    for (int ss = 0; ss < 4; ++ss)
        #pragma unroll
        for (int r = 0; r < 4; ++r) lp[ss][r] = 0.f;

    for (int sb = phase; 2 * sb <= itB; sb += 4) {
        #pragma unroll
        for (int u = 0; u < 2; ++u) {
            const int jt = 2 * sb + u;
            if (jt > itB) break;
            const int j0 = jt * 16;
            const bool actA = (jt <= itA);
            half4v kf[2][4];
            #pragma unroll
            for (int e = 0; e < 2; ++e) {
                const _Float16* krow = Kh + ((bh0 + h0 + e) * N_ + j0 + l16) * D_ + 4 * lg;
                #pragma unroll
                for (int kk = 0; kk < 4; ++kk) kf[e][kk] = *(const half4v*)(krow + kk * 16);
            }
            #pragma unroll
            for (int s = 0; s < 2; ++s) {
                if (s == 0 && !actA) continue;
                #pragma unroll
                for (int e = 0; e < 2; ++e) {
                    f32x4 acc = {0.f, 0.f, 0.f, 0.f};
                    #pragma unroll
                    for (int kk = 0; kk < 4; ++kk)
                        acc = __builtin_amdgcn_mfma_f32_16x16x16f16(qf[s][e][kk], kf[e][kk], acc, 0, 0, 0);
                    #pragma unroll
                    for (int r = 0; r < 4; ++r)
                        Ss[(s * 16 + 4 * lg + r) * SS_R + l16 * 20 + h0 + e] = (_Float16)acc[r];
                }
            }
            __syncthreads();
            #pragma unroll
            for (int ss = 0; ss < 4; ++ss) {
                const int strip = ss >> 1;
                if (strip == 0 && !actA) continue;
                const int sii = (ss & 1) * 8 + w;
                const int its = strip ? itB : itA;
                half4v sfrag = *(const half4v*)&Ss[(strip * 16 + sii) * SS_R + l16 * 20 + 4 * lg];
                f32x4 z = {0.f, 0.f, 0.f, 0.f};
                f32x4 m1 = __builtin_amdgcn_mfma_f32_16x16x16f16(wpre_f, sfrag, z, 0, 0, 0);
                if ((jt < its) || (l16 <= sii)) {
                    #pragma unroll
                    for (int r = 0; r < 4; ++r) lp[ss][r] += __expf(m1[r]);
                }
            }
            __syncthreads();
        }
    }

    #pragma unroll
    for (int ss = 0; ss < 4; ++ss) {
        const int strip = ss >> 1;
        const int sii = (ss & 1) * 8 + w;
        const int i0s = strip ? i0B : i0A;
        #pragma unroll
        for (int r = 0; r < 4; ++r) {
            float val = lp[ss][r];
            val += __shfl_xor(val, 1, 64);
            val += __shfl_xor(val, 2, 64);
            val += __shfl_xor(val, 4, 64);
            val += __shfl_xor(val, 8, 64);
            if (l16 == 0)
                atomicAdd(&lbuf[(bh0 + 4 * lg + r) * N_ + i0s + sii], val);
        }
    }
}

// ---------------- phase kernel B: partial outputs (plain stores) ----------------
__global__ __launch_bounds__(512, 2)
void attend_out_p(const float* __restrict__ q, const _Float16* __restrict__ Kh,
                  const _Float16* __restrict__ VT, const float* __restrict__ Wpre,
                  const float* __restrict__ Wpost, const float* __restrict__ lbuf,
                  float* __restrict__ part) {
    __shared__ _Float16 Ss[32 * SS_R];    // 20,992 B
    __shared__ _Float16 A2s[16 * A2_R];   // 20,736 B

    const int slot = xcd_slot(blockIdx.x);
    const int b = slot >> 7;
    const int r7 = slot & 127;
    const int m = r7 >> 2, phase = r7 & 3;
    const int itA = m, itB = 63 - m;
    const int i0A = m * 16, i0B = itB * 16;

    const int t = threadIdx.x;
    const int lane = t & 63, w = t >> 6;
    const int l16 = lane & 15, lg = lane >> 4;
    const int h0 = 2 * w;
    const size_t bh0 = (size_t)b * H_;

    const half4v wpre_f  = cvt4(*(const f32x4*)(Wpre  + l16 * 16 + 4 * lg));
    const half4v wpost_f = cvt4(*(const f32x4*)(Wpost + l16 * 16 + 4 * lg));

    half4v qf[2][2][4];
    #pragma unroll
    for (int s = 0; s < 2; ++s) {
        const int i0s = s ? i0B : i0A;
        #pragma unroll
        for (int e = 0; e < 2; ++e) {
            const float* qrow = q + ((bh0 + h0 + e) * N_ + i0s + l16) * D_;
            #pragma unroll
            for (int kk = 0; kk < 4; ++kk) {
                f32x4 qv = *(const f32x4*)(qrow + kk * 16 + 4 * lg);
                half4v hv;
                #pragma unroll
                for (int x = 0; x < 4; ++x) hv[x] = (_Float16)(qv[x] * 0.125f);
                qf[s][e][kk] = hv;
            }
        }
    }

    // 1/l for softmax head 4lg+r, task row (strip, sii)
    float lrecip[4][4];
    #pragma unroll
    for (int ss = 0; ss < 4; ++ss) {
        const int strip = ss >> 1;
        const int sii = (ss & 1) * 8 + w;
        const int i0s = strip ? i0B : i0A;
        #pragma unroll
        for (int r = 0; r < 4; ++r)
            lrecip[ss][r] = 1.0f / lbuf[(bh0 + 4 * lg + r) * N_ + i0s + sii];
    }

    f32x4 oacc[2][2][4];
    #pragma unroll
    for (int s = 0; s < 2; ++s)
        #pragma unroll
        for (int e = 0; e < 2; ++e)
            #pragma unroll
            for (int ds = 0; ds < 4; ++ds)
                oacc[s][e][ds] = (f32x4){0.f, 0.f, 0.f, 0.f};

    for (int sb = phase; 2 * sb <= itB; sb += 4) {
        #pragma unroll
        for (int u = 0; u < 2; ++u) {
            const int jt = 2 * sb + u;
            if (jt > itB) break;
            const int j0 = jt * 16;
            const bool actA = (jt <= itA);
            half4v kf[2][4];
            #pragma unroll
            for (int e = 0; e < 2; ++e) {
                const _Float16* krow = Kh + ((bh0 + h0 + e) * N_ + j0 + l16) * D_ + 4 * lg;
                #pragma unroll
                for (int kk = 0; kk < 4; ++kk) kf[e][kk] = *(const half4v*)(krow + kk * 16);
            }
            half4v vf[2][4];
            #pragma unroll
            for (int e = 0; e < 2; ++e) {
                #pragma unroll
                for (int ds = 0; ds < 4; ++ds)
                    vf[e][ds] = *(const half4v*)(VT + ((bh0 + h0 + e) * D_ + ds * 16 + l16) * N_ + j0 + 4 * lg);
            }
            // QK^T -> Ss
            #pragma unroll
            for (int s = 0; s < 2; ++s) {
                if (s == 0 && !actA) continue;
                #pragma unroll
                for (int e = 0; e < 2; ++e) {
                    f32x4 acc = {0.f, 0.f, 0.f, 0.f};
                    #pragma unroll
                    for (int kk = 0; kk < 4; ++kk)
                        acc = __builtin_amdgcn_mfma_f32_16x16x16f16(qf[s][e][kk], kf[e][kk], acc, 0, 0, 0);
                    #pragma unroll
                    for (int r = 0; r < 4; ++r)
                        Ss[(s * 16 + 4 * lg + r) * SS_R + l16 * 20 + h0 + e] = (_Float16)acc[r];
                }
            }
            __syncthreads();
            // mix1 -> exp/mask/normalize -> mix2 -> A2s
            #pragma unroll
            for (int ss = 0; ss < 4; ++ss) {
                const int strip = ss >> 1;
                if (strip == 0 && !actA) continue;
                const int sii = (ss & 1) * 8 + w;
                const int its = strip ? itB : itA;
                half4v sfrag = *(const half4v*)&Ss[(strip * 16 + sii) * SS_R + l16 * 20 + 4 * lg];
                f32x4 z = {0.f, 0.f, 0.f, 0.f};
                f32x4 m1 = __builtin_amdgcn_mfma_f32_16x16x16f16(wpre_f, sfrag, z, 0, 0, 0);
                const bool ok = (jt < its) || (l16 <= sii);
                half4v pfrag;
                #pragma unroll
                for (int r = 0; r < 4; ++r)
                    pfrag[r] = (_Float16)(ok ? __expf(m1[r]) * lrecip[ss][r] : 0.f);
                f32x4 m2 = __builtin_amdgcn_mfma_f32_16x16x16f16(wpost_f, pfrag, z, 0, 0, 0);
                #pragma unroll
                for (int r = 0; r < 4; ++r)
                    A2s[(4 * lg + r) * A2_R + (strip * 16 + sii) * 20 + l16] = (_Float16)m2[r];
            }
            __syncthreads();
            // PV
            #pragma unroll
            for (int s = 0; s < 2; ++s) {
                if (s == 0 && !actA) continue;
                #pragma unroll
                for (int e = 0; e < 2; ++e) {
                    half4v bfrag = *(const half4v*)&A2s[(h0 + e) * A2_R + (s * 16 + l16) * 20 + 4 * lg];
                    #pragma unroll
                    for (int ds = 0; ds < 4; ++ds)
                        oacc[s][e][ds] = __builtin_amdgcn_mfma_f32_16x16x16f16(vf[e][ds], bfrag, oacc[s][e][ds], 0, 0, 0);
                }
            }
        }
    }

    // partial-out plain stores: [slot][strip][h][i(16)][d(64)]
    float* pb = part + (size_t)slot * 32768;
    #pragma unroll
    for (int s = 0; s < 2; ++s) {
        #pragma unroll
        for (int e = 0; e < 2; ++e) {
            const int h = h0 + e;
            float* prow = pb + ((size_t)((s * 16 + h) * 16) + l16) * 64;
            #pragma unroll
            for (int ds = 0; ds < 4; ++ds)
                *(f32x4*)&prow[ds * 16 + 4 * lg] = oacc[s][e][ds];
        }
    }
}

// ---------------- reduce: out = sum over 4 phases ----------------
__global__ __launch_bounds__(256)
void reduce_out(const float* __restrict__ part, float* __restrict__ out) {
    const int b = blockIdx.x >> 6, it = blockIdx.x & 63;
    const int m = (it < 32) ? it : 63 - it;
    const int s = (it < 32) ? 0 : 1;
    const size_t pslot = ((size_t)(b * 32 + m)) * 4;
    const int t = threadIdx.x;
    for (int iter = 0; iter < 16; ++iter) {
        const int f = (iter * 256 + t) * 4;            // flat f32 index, x4 aligned
        const int h = f >> 10, rem = f & 1023;
        const int i = rem >> 6, d = rem & 63;
        const size_t poff = ((size_t)(s * 16 + h) * 16 + i) * 64 + d;
        f32x4 a0 = *(const f32x4*)(part + (pslot + 0) * 32768 + poff);
        f32x4 a1 = *(const f32x4*)(part + (pslot + 1) * 32768 + poff);
        f32x4 a2 = *(const f32x4*)(part + (pslot + 2) * 32768 + poff);
        f32x4 a3 = *(const f32x4*)(part + (pslot + 3) * 32768 + poff);
        f32x4 sum = (a0 + a1) + (a2 + a3);
        *(f32x4*)(out + (((size_t)(b * H_ + h)) * N_ + it * 16 + i) * D_ + d) = sum;
    }
}

// ---------------- fallback: R6 fused mirror-pair kernel (verified) ----------------
template<bool WS>
__global__ __launch_bounds__(512, 2)
void attend_fused(const float* __restrict__ q, const float* __restrict__ k,
                  const float* __restrict__ v, const _Float16* __restrict__ Kh,
                  const _Float16* __restrict__ VT, const float* __restrict__ Wpre,
                  const float* __restrict__ Wpost, float* __restrict__ out) {
    __shared__ _Float16 Ss[32 * SS_R];
    __shared__ _Float16 A2s[16 * A2_R];

    const int t = threadIdx.x;
    const int b = blockIdx.x >> 5;
    const int m = blockIdx.x & 31;
    const int itA = m, itB = 63 - m;
    const int i0A = m * 16, i0B = (63 - m) * 16;

    const int lane = t & 63, w = t >> 6;
    const int l16 = lane & 15, lg = lane >> 4;
    const int h0 = 2 * w;
    const size_t bh0 = (size_t)b * H_;

    const half4v wpre_f  = cvt4(*(const f32x4*)(Wpre  + l16 * 16 + 4 * lg));
    const half4v wpost_f = cvt4(*(const f32x4*)(Wpost + l16 * 16 + 4 * lg));

    half4v qf[2][2][4];
    #pragma unroll
    for (int s = 0; s < 2; ++s) {
        const int i0s = s ? i0B : i0A;
        #pragma unroll
        for (int e = 0; e < 2; ++e) {
            const float* qrow = q + ((bh0 + h0 + e) * N_ + i0s + l16) * D_;
            #pragma unroll
            for (int kk = 0; kk < 4; ++kk) {
                f32x4 qv = *(const f32x4*)(qrow + kk * 16 + 4 * lg);
                half4v hv;
                #pragma unroll
                for (int x = 0; x < 4; ++x) hv[x] = (_Float16)(qv[x] * 0.125f);
                qf[s][e][kk] = hv;
            }
        }
    }

    float lp[4][4];
    #pragma unroll
    for (int ss = 0; ss < 4; ++ss)
        #pragma unroll
        for (int r = 0; r < 4; ++r) lp[ss][r] = 0.f;

    for (int jt = 0; jt <= itB; ++jt) {
        const int j0 = jt * 16;
        const bool actA = (jt <= itA);
        half4v kf[2][4];
        #pragma unroll
        for (int e = 0; e < 2; ++e) {
            if (WS) {
                const _Float16* krow = Kh + ((bh0 + h0 + e) * N_ + j0 + l16) * D_ + 4 * lg;
                #pragma unroll
                for (int kk = 0; kk < 4; ++kk) kf[e][kk] = *(const half4v*)(krow + kk * 16);
            } else {
                const float* krow = k + ((bh0 + h0 + e) * N_ + j0 + l16) * D_ + 4 * lg;
                #pragma unroll
                for (int kk = 0; kk < 4; ++kk) kf[e][kk] = cvt4(*(const f32x4*)(krow + kk * 16));
            }
        }
        #pragma unroll
        for (int s = 0; s < 2; ++s) {
            if (s == 0 && !actA) continue;
            #pragma unroll
            for (int e = 0; e < 2; ++e) {
                f32x4 acc = {0.f, 0.f, 0.f, 0.f};
                #pragma unroll
                for (int kk = 0; kk < 4; ++kk)
                    acc = __builtin_amdgcn_mfma_f32_16x16x16f16(qf[s][e][kk], kf[e][kk], acc, 0, 0, 0);
                #pragma unroll
                for (int r = 0; r < 4; ++r)
                    Ss[(s * 16 + 4 * lg + r) * SS_R + l16 * 20 + h0 + e] = (_Float16)acc[r];
            }
        }
        __syncthreads();
        #pragma unroll
        for (int ss = 0; ss < 4; ++ss) {
            const int strip = ss >> 1;
            if (strip == 0 && !actA) continue;
            const int sii = (ss & 1) * 8 + w;
            const int its = strip ? itB : itA;
            half4v sfrag = *(const half4v*)&Ss[(strip * 16 + sii) * SS_R + l16 * 20 + 4 * lg];
            f32x4 z = {0.f, 0.f, 0.f, 0.f};
            f32x4 m1 = __builtin_amdgcn_mfma_f32_16x16x16f16(wpre_f, sfrag, z, 0, 0, 0);
            if ((jt < its) || (l16 <= sii)) {
                #pragma unroll
                for (int r = 0; r < 4; ++r) lp[ss][r] += __expf(m1[r]);
            }
        }
        __syncthreads();
    }

    float lrec[4][4];
    #pragma unroll
    for (int ss = 0; ss < 4; ++ss) {
        #pragma unroll
        for (int r = 0; r < 4; ++r) {
            float val = lp[ss][r];
            val += __shfl_xor(val, 1, 64);
            val += __shfl_xor(val, 2, 64);
            val += __shfl_xor(val, 4, 64);
            val += __shfl_xor(val, 8, 64);
            lrec[ss][r] = 1.0f / val;
        }
    }

    f32x4 oacc[2][2][4];
    #pragma unroll
    for (int s = 0; s < 2; ++s)
        #pragma unroll
        for (int e = 0; e < 2; ++e)
            #pragma unroll
            for (int ds = 0; ds < 4; ++ds)
                oacc[s][e][ds] = (f32x4){0.f, 0.f, 0.f, 0.f};

    for (int jt = 0; jt <= itB; ++jt) {
        const int j0 = jt * 16;
        const bool actA = (jt <= itA);
        half4v kf[2][4];
        #pragma unroll
        for (int e = 0; e < 2; ++e) {
            if (WS) {
                const _Float16* krow = Kh + ((bh0 + h0 + e) * N_ + j0 + l16) * D_ + 4 * lg;
                #pragma unroll
                for (int kk = 0; kk < 4; ++kk) kf[e][kk] = *(const half4v*)(krow + kk * 16);
            } else {
                const float* krow = k + ((bh0 + h0 + e) * N_ + j0 + l16) * D_ + 4 * lg;
                #pragma unroll
                for (int kk = 0; kk < 4; ++kk) kf[e][kk] = cvt4(*(const f32x4*)(krow + kk * 16));
            }
        }
        half4v vf[2][4];
        #pragma unroll
        for (int e = 0; e < 2; ++e) {
            #pragma unroll
            for (int ds = 0; ds < 4; ++ds) {
                if (WS) {
                    vf[e][ds] = *(const half4v*)(VT + ((bh0 + h0 + e) * D_ + ds * 16 + l16) * N_ + j0 + 4 * lg);
                } else {
                    f32x4 vv;
                    #pragma unroll
                    for (int x = 0; x < 4; ++x)
                        vv[x] = v[((bh0 + h0 + e) * N_ + j0 + 4 * lg + x) * D_ + ds * 16 + l16];
                    vf[e][ds] = cvt4(vv);
                }
            }
        }
        #pragma unroll
        for (int s = 0; s < 2; ++s) {
            if (s == 0 && !actA) continue;
            #pragma unroll
            for (int e = 0; e < 2; ++e) {
                f32x4 acc = {0.f, 0.f, 0.f, 0.f};
                #pragma unroll
                for (int kk = 0; kk < 4; ++kk)
                    acc = __builtin_amdgcn_mfma_f32_16x16x16f16(qf[s][e][kk], kf[e][kk], acc, 0, 0, 0);
                #pragma unroll
                for (int r = 0; r < 4; ++r)
                    Ss[(s * 16 + 4 * lg + r) * SS_R + l16 * 20 + h0 + e] = (_Float16)acc[r];
            }
        }
        __syncthreads();
        #pragma unroll
        for (int ss = 0; ss < 4; ++ss) {
            const int strip = ss >> 1;
            if (strip == 0 && !actA) continue;
            const int sii = (ss & 1) * 8 + w;
            const int its = strip ? itB : itA;
            half4v sfrag = *(const half4v*)&Ss[(strip * 16 + sii) * SS_R + l16 * 20 + 4 * lg];
            f32x4 z = {0.f, 0.f, 0.f, 0.f};
            f32x4 m1 = __builtin_amdgcn_mfma_f32_16x16x16f16(wpre_f, sfrag, z, 0, 0, 0);
            const bool ok = (jt < its) || (l16 <= sii);
            half4v pfrag;
            #pragma unroll
            for (int r = 0; r < 4; ++r)
                pfrag[r] = (_Float16)(ok ? __expf(m1[r]) * lrec[ss][r] : 0.f);
            f32x4 m2 = __builtin_amdgcn_mfma_f32_16x16x16f16(wpost_f, pfrag, z, 0, 0, 0);
            #pragma unroll
            for (int r = 0; r < 4; ++r)
                A2s[(4 * lg + r) * A2_R + (strip * 16 + sii) * 20 + l16] = (_Float16)m2[r];
        }
        __syncthreads();
        #pragma unroll
        for (int s = 0; s < 2; ++s) {
            if (s == 0 && !actA) continue;
            #pragma unroll
            for (int e = 0; e < 2; ++e) {
                half4v bfrag = *(const half4v*)&A2s[(h0 + e) * A2_R + (s * 16 + l16) * 20 + 4 * lg];
                #pragma unroll
                for (int ds = 0; ds < 4; ++ds)
                    oacc[s][e][ds] = __builtin_amdgcn_mfma_f32_16x16x16f16(vf[e][ds], bfrag, oacc[s][e][ds], 0, 0, 0);
            }
        }
    }

    #pragma unroll
    for (int s = 0; s < 2; ++s) {
        const int i0s = s ? i0B : i0A;
        #pragma unroll
        for (int e = 0; e < 2; ++e) {
            float* orow = out + ((bh0 + h0 + e) * N_ + i0s + l16) * D_;
            #pragma unroll
            for (int ds = 0; ds < 4; ++ds)
                *(f32x4*)&orow[ds * 16 + 4 * lg] = oacc[s][e][ds];
        }
    }
}

extern "C" void kernel_launch(void* const* d_in, const int* in_sizes, int n_in,
                              void* d_out, int out_size, void* d_ws, size_t ws_size,
                              hipStream_t stream) {
    const float* q     = (const float*)d_in[0];
    const float* k     = (const float*)d_in[1];
    const float* v     = (const float*)d_in[2];
    const float* Wpre  = (const float*)d_in[3];
    const float* Wpost = (const float*)d_in[4];
    float* out  = (float*)d_out;
    _Float16* VT  = (_Float16*)((char*)d_ws + VT_OFF);
    _Float16* Kh  = (_Float16*)((char*)d_ws + KH_OFF);
    float*    lbuf = (float*)((char*)d_ws + LB_OFF);
    float*    part = (float*)((char*)d_ws + PT_OFF);

    if (ws_size >= WS_FULL) {
        prep_vt<<<dim3(B_ * H_ * (N_ / 64)), dim3(256), 0, stream>>>(v, VT);
        prep_kh<<<dim3((B_ * H_ * N_ * D_) / (256 * 8)), dim3(256), 0, stream>>>(k, Kh);
        hipMemsetAsync((char*)d_ws + LB_OFF, 0, LB_SZ, stream);
        attend_lsum_p<<<dim3(512), dim3(512), 0, stream>>>(q, Kh, Wpre, lbuf);
        attend_out_p<<<dim3(512), dim3(512), 0, stream>>>(q, Kh, VT, Wpre, Wpost, lbuf, part);
        reduce_out<<<dim3(B_ * 64), dim3(256), 0, stream>>>(part, out);
    } else if (ws_size >= WS_MIN) {
        prep_vt<<<dim3(B_ * H_ * (N_ / 64)), dim3(256), 0, stream>>>(v, VT);
        prep_kh<<<dim3((B_ * H_ * N_ * D_) / (256 * 8)), dim3(256), 0, stream>>>(k, Kh);
        attend_fused<true><<<dim3(B_ * 32), dim3(512), 0, stream>>>(q, k, v, Kh, VT, Wpre, Wpost, out);
    } else {
        attend_fused<false><<<dim3(B_ * 32), dim3(512), 0, stream>>>(q, k, v, Kh, VT, Wpre, Wpost, out);
    }
}

// Round 8
// 183.686 us; speedup vs baseline: 2.1640x; 1.1910x over previous
//
#include <hip/hip_runtime.h>
#include <stdint.h>

#define B_  4
#define H_  16
#define N_  1024
#define D_  64
#define SS_R 328   // halfs per i-row of Ss: [i in 0..32)][j*20 + h], +8 pad
#define A2_R 328   // halfs per g-row of A2s: [g][i*20 + j], +8 pad

typedef _Float16 half4v __attribute__((ext_vector_type(4)));
typedef _Float16 half8v __attribute__((ext_vector_type(8)));
typedef float    f32x4  __attribute__((ext_vector_type(4)));

// workspace layout (bytes)
#define VT_OFF   0
#define VT_SZ    (B_ * H_ * D_ * N_ * 2)             // 8 MB
#define LB_OFF   (VT_OFF + VT_SZ)
#define LB_SZ    (B_ * H_ * N_ * 4)                  // 256 KB
#define E_OFF    (LB_OFF + LB_SZ)
#define E_SZ     ((size_t)B_ * 2080 * 4096 * 2)      // 65 MB causal-packed E
#define WS_NEED  ((size_t)E_OFF + E_SZ)              // 73.25 MB (< proven 80.25)

__device__ __forceinline__ half4v cvt4(f32x4 v) {
    half4v h;
    h[0] = (_Float16)v[0]; h[1] = (_Float16)v[1];
    h[2] = (_Float16)v[2]; h[3] = (_Float16)v[3];
    return h;
}

// decode blockIdx (0..511) -> slot grouped per XCD (consecutive slots same XCD)
__device__ __forceinline__ int xcd_slot(int x) { return (x >> 3) + (x & 7) * 64; }

// ---------------- prep: V transpose to f16 VT[b,h,d,j] ----------------
__global__ __launch_bounds__(256)
void prep_vt(const float* __restrict__ v, _Float16* __restrict__ VT) {
    __shared__ float T[64 * 67];
    const int t = threadIdx.x;
    const int bh = blockIdx.x >> 4, jb = blockIdx.x & 15, j0 = jb * 64;
    const float* src = v + ((size_t)bh * N_ + j0) * D_;
    #pragma unroll
    for (int m = 0; m < 4; ++m) {
        const int flat = m * 1024 + t * 4;
        const int j = flat >> 6, d0 = flat & 63;
        f32x4 val = *(const f32x4*)(src + flat);
        #pragma unroll
        for (int e = 0; e < 4; ++e) T[j * 67 + d0 + e] = val[e];
    }
    __syncthreads();
    const int d = t >> 2, jq = t & 3;
    half8v a, b2;
    #pragma unroll
    for (int jj = 0; jj < 8; ++jj) a[jj]  = (_Float16)T[(16 * jq + jj) * 67 + d];
    #pragma unroll
    for (int jj = 0; jj < 8; ++jj) b2[jj] = (_Float16)T[(16 * jq + 8 + jj) * 67 + d];
    _Float16* dst = VT + ((size_t)bh * D_ + d) * N_ + j0 + jq * 16;
    *(half8v*)dst = a;
    *(half8v*)(dst + 8) = b2;
}

// ---------------- sweep 1: l (atomic) + E cache (f16, causal-packed) ----------------
// grid 512: phased mirror-pairs (proven balance). Ss double-buffered: 1 barrier/body.
__global__ __launch_bounds__(512, 2)
void attend_sweep1(const float* __restrict__ q, const float* __restrict__ k,
                   const float* __restrict__ Wpre, float* __restrict__ lbuf,
                   _Float16* __restrict__ Ebuf) {
    __shared__ _Float16 Ss[2][32 * SS_R];   // 41,984 B

    const int slot = xcd_slot(blockIdx.x);
    const int b = slot >> 7;
    const int r7 = slot & 127;
    const int m = r7 >> 2, phase = r7 & 3;
    const int itA = m, itB = 63 - m;
    const int i0A = m * 16, i0B = itB * 16;
    const int triA = itA * (itA + 1) / 2, triB = itB * (itB + 1) / 2;

    const int t = threadIdx.x;
    const int lane = t & 63, w = t >> 6;        // 8 waves
    const int l16 = lane & 15, lg = lane >> 4;
    const int h0 = 2 * w;
    const size_t bh0 = (size_t)b * H_;
    _Float16* Eb = Ebuf + (size_t)b * 2080 * 4096;

    const half4v wpre_f = cvt4(*(const f32x4*)(Wpre + l16 * 16 + 4 * lg));

    half4v qf[2][2][4];
    #pragma unroll
    for (int s = 0; s < 2; ++s) {
        const int i0s = s ? i0B : i0A;
        #pragma unroll
        for (int e = 0; e < 2; ++e) {
            const float* qrow = q + ((bh0 + h0 + e) * N_ + i0s + l16) * D_;
            #pragma unroll
            for (int kk = 0; kk < 4; ++kk) {
                f32x4 qv = *(const f32x4*)(qrow + kk * 16 + 4 * lg);
                half4v hv;
                #pragma unroll
                for (int x = 0; x < 4; ++x) hv[x] = (_Float16)(qv[x] * 0.125f);
                qf[s][e][kk] = hv;
            }
        }
    }

    float lp[4][4];
    #pragma unroll
    for (int ss = 0; ss < 4; ++ss)
        #pragma unroll
        for (int r = 0; r < 4; ++r) lp[ss][r] = 0.f;

    int pbuf = 0;
    for (int sb = phase; 2 * sb <= itB; sb += 4) {
        #pragma unroll
        for (int u = 0; u < 2; ++u) {
            const int jt = 2 * sb + u;
            if (jt > itB) break;
            const int j0 = jt * 16;
            const bool actA = (jt <= itA);
            // K fragments (f32 -> f16)
            half4v kf[2][4];
            #pragma unroll
            for (int e = 0; e < 2; ++e) {
                const float* krow = k + ((bh0 + h0 + e) * N_ + j0 + l16) * D_ + 4 * lg;
                #pragma unroll
                for (int kk = 0; kk < 4; ++kk) kf[e][kk] = cvt4(*(const f32x4*)(krow + kk * 16));
            }
            // QK^T -> Ss[pbuf]
            #pragma unroll
            for (int s = 0; s < 2; ++s) {
                if (s == 0 && !actA) continue;
                #pragma unroll
                for (int e = 0; e < 2; ++e) {
                    f32x4 acc = {0.f, 0.f, 0.f, 0.f};
                    #pragma unroll
                    for (int kk = 0; kk < 4; ++kk)
                        acc = __builtin_amdgcn_mfma_f32_16x16x16f16(qf[s][e][kk], kf[e][kk], acc, 0, 0, 0);
                    #pragma unroll
                    for (int r = 0; r < 4; ++r)
                        Ss[pbuf][(s * 16 + 4 * lg + r) * SS_R + l16 * 20 + h0 + e] = (_Float16)acc[r];
                }
            }
            __syncthreads();
            // mix1 -> exp/mask -> E store + l accumulate
            #pragma unroll
            for (int ss = 0; ss < 4; ++ss) {
                const int strip = ss >> 1;
                if (strip == 0 && !actA) continue;
                const int sii = (ss & 1) * 8 + w;
                const int its = strip ? itB : itA;
                const int tri = strip ? triB : triA;
                half4v sfrag = *(const half4v*)&Ss[pbuf][(strip * 16 + sii) * SS_R + l16 * 20 + 4 * lg];
                f32x4 z = {0.f, 0.f, 0.f, 0.f};
                f32x4 m1 = __builtin_amdgcn_mfma_f32_16x16x16f16(wpre_f, sfrag, z, 0, 0, 0);
                const bool ok = (jt < its) || (l16 <= sii);
                half4v ev;
                #pragma unroll
                for (int r = 0; r < 4; ++r) {
                    const float e_ = ok ? __expf(m1[r]) : 0.f;
                    lp[ss][r] += e_;
                    ev[r] = (_Float16)e_;
                }
                *(half4v*)(Eb + (size_t)(tri + jt) * 4096 + (sii * 16 + l16) * 16 + 4 * lg) = ev;
            }
            pbuf ^= 1;
        }
    }

    #pragma unroll
    for (int ss = 0; ss < 4; ++ss) {
        const int strip = ss >> 1;
        const int sii = (ss & 1) * 8 + w;
        const int i0s = strip ? i0B : i0A;
        #pragma unroll
        for (int r = 0; r < 4; ++r) {
            float val = lp[ss][r];
            val += __shfl_xor(val, 1, 64);
            val += __shfl_xor(val, 2, 64);
            val += __shfl_xor(val, 4, 64);
            val += __shfl_xor(val, 8, 64);
            if (l16 == 0)
                atomicAdd(&lbuf[(bh0 + 4 * lg + r) * N_ + i0s + sii], val);
        }
    }
}

// ---------------- sweep 2: out = Wpost·(E/l)·V, no QK^T, plain stores ----------------
// grid 512: x -> (it descending, b, d-half). One barrier/body; E & V prefetched.
__global__ __launch_bounds__(512, 2)
void attend_sweep2(const _Float16* __restrict__ Ebuf, const _Float16* __restrict__ VT,
                   const float* __restrict__ Wpost, const float* __restrict__ lbuf,
                   float* __restrict__ out) {
    __shared__ _Float16 A2s[2][16 * A2_R];   // 20,992 B

    const int x = blockIdx.x;
    const int it = 63 - (x >> 3);
    const int sub = x & 7;
    const int b = sub >> 1, dh = sub & 1;
    const int i0 = it * 16;

    const int t = threadIdx.x;
    const int lane = t & 63, w = t >> 6;        // 8 waves
    const int l16 = lane & 15, lg = lane >> 4;
    const int h0 = 2 * w;
    const size_t bh0 = (size_t)b * H_;

    const half4v wpost_f = cvt4(*(const f32x4*)(Wpost + l16 * 16 + 4 * lg));

    // 1/l for softmax head 4lg+r at rows i0+sii (sii = ss*8+w)
    float lrecip[2][4];
    #pragma unroll
    for (int ss = 0; ss < 2; ++ss) {
        const int sii = ss * 8 + w;
        #pragma unroll
        for (int r = 0; r < 4; ++r)
            lrecip[ss][r] = 1.0f / lbuf[(bh0 + 4 * lg + r) * N_ + i0 + sii];
    }

    const _Float16* Eb = Ebuf + ((size_t)b * 2080 + (size_t)it * (it + 1) / 2) * 4096;

    f32x4 oacc[2][2];
    #pragma unroll
    for (int e = 0; e < 2; ++e)
        #pragma unroll
        for (int ds = 0; ds < 2; ++ds)
            oacc[e][ds] = (f32x4){0.f, 0.f, 0.f, 0.f};

    int pb = 0;
    // prologue: E(0)
    half4v ef[2];
    #pragma unroll
    for (int ss = 0; ss < 2; ++ss)
        ef[ss] = *(const half4v*)(Eb + ((ss * 8 + w) * 16 + l16) * 16 + 4 * lg);

    for (int jt = 0; jt <= it; ++jt) {
        const int j0 = jt * 16;
        // V^T fragments (in flight under mix2 + barrier)
        half4v vf[2][2];
        #pragma unroll
        for (int e = 0; e < 2; ++e)
            #pragma unroll
            for (int ds = 0; ds < 2; ++ds)
                vf[e][ds] = *(const half4v*)(VT + ((bh0 + h0 + e) * D_ + dh * 32 + ds * 16 + l16) * (size_t)N_ + j0 + 4 * lg);
        // mix2 from prefetched E
        #pragma unroll
        for (int ss = 0; ss < 2; ++ss) {
            const int sii = ss * 8 + w;
            half4v pf;
            #pragma unroll
            for (int r = 0; r < 4; ++r)
                pf[r] = (_Float16)((float)ef[ss][r] * lrecip[ss][r]);
            f32x4 z = {0.f, 0.f, 0.f, 0.f};
            f32x4 m2 = __builtin_amdgcn_mfma_f32_16x16x16f16(wpost_f, pf, z, 0, 0, 0);
            #pragma unroll
            for (int r = 0; r < 4; ++r)
                A2s[pb][(4 * lg + r) * A2_R + sii * 20 + l16] = (_Float16)m2[r];
        }
        // prefetch E(jt+1) — stays in flight across the barrier
        if (jt < it) {
            #pragma unroll
            for (int ss = 0; ss < 2; ++ss)
                ef[ss] = *(const half4v*)(Eb + (size_t)(jt + 1) * 4096 + ((ss * 8 + w) * 16 + l16) * 16 + 4 * lg);
        }
        __syncthreads();
        // PV
        #pragma unroll
        for (int e = 0; e < 2; ++e) {
            const int g = h0 + e;
            half4v bfrag = *(const half4v*)&A2s[pb][g * A2_R + l16 * 20 + 4 * lg];
            #pragma unroll
            for (int ds = 0; ds < 2; ++ds)
                oacc[e][ds] = __builtin_amdgcn_mfma_f32_16x16x16f16(vf[e][ds], bfrag, oacc[e][ds], 0, 0, 0);
        }
        pb ^= 1;
    }

    // plain stores — this WG exclusively owns (b, it-rows, all g, this d-half)
    #pragma unroll
    for (int e = 0; e < 2; ++e) {
        float* orow = out + ((bh0 + h0 + e) * N_ + i0 + l16) * D_;
        #pragma unroll
        for (int ds = 0; ds < 2; ++ds)
            *(f32x4*)&orow[dh * 32 + ds * 16 + 4 * lg] = oacc[e][ds];
    }
}

// ---------------- fallback: fused mirror-pair kernel (ws-free, verified R6) ----------------
__global__ __launch_bounds__(512, 2)
void attend_fused(const float* __restrict__ q, const float* __restrict__ k,
                  const float* __restrict__ v, const float* __restrict__ Wpre,
                  const float* __restrict__ Wpost, float* __restrict__ out) {
    __shared__ _Float16 Ss[32 * SS_R];
    __shared__ _Float16 A2s[16 * 648];

    const int t = threadIdx.x;
    const int b = blockIdx.x >> 5;
    const int m = blockIdx.x & 31;
    const int itA = m, itB = 63 - m;
    const int i0A = m * 16, i0B = (63 - m) * 16;

    const int lane = t & 63, w = t >> 6;
    const int l16 = lane & 15, lg = lane >> 4;
    const int h0 = 2 * w;
    const size_t bh0 = (size_t)b * H_;

    const half4v wpre_f  = cvt4(*(const f32x4*)(Wpre  + l16 * 16 + 4 * lg));
    const half4v wpost_f = cvt4(*(const f32x4*)(Wpost + l16 * 16 + 4 * lg));

    half4v qf[2][2][4];
    #pragma unroll
    for (int s = 0; s < 2; ++s) {
        const int i0s = s ? i0B : i0A;
        #pragma unroll
        for (int e = 0; e < 2; ++e) {
            const float* qrow = q + ((bh0 + h0 + e) * N_ + i0s + l16) * D_;
            #pragma unroll
            for (int kk = 0; kk < 4; ++kk) {
                f32x4 qv = *(const f32x4*)(qrow + kk * 16 + 4 * lg);
                half4v hv;
                #pragma unroll
                for (int x = 0; x < 4; ++x) hv[x] = (_Float16)(qv[x] * 0.125f);
                qf[s][e][kk] = hv;
            }
        }
    }

    float lp[4][4];
    #pragma unroll
    for (int ss = 0; ss < 4; ++ss)
        #pragma unroll
        for (int r = 0; r < 4; ++r) lp[ss][r] = 0.f;

    for (int jt = 0; jt <= itB; ++jt) {
        const int j0 = jt * 16;
        const bool actA = (jt <= itA);
        half4v kf[2][4];
        #pragma unroll
        for (int e = 0; e < 2; ++e) {
            const float* krow = k + ((bh0 + h0 + e) * N_ + j0 + l16) * D_ + 4 * lg;
            #pragma unroll
            for (int kk = 0; kk < 4; ++kk) kf[e][kk] = cvt4(*(const f32x4*)(krow + kk * 16));
        }
        #pragma unroll
        for (int s = 0; s < 2; ++s) {
            if (s == 0 && !actA) continue;
            #pragma unroll
            for (int e = 0; e < 2; ++e) {
                f32x4 acc = {0.f, 0.f, 0.f, 0.f};
                #pragma unroll
                for (int kk = 0; kk < 4; ++kk)
                    acc = __builtin_amdgcn_mfma_f32_16x16x16f16(qf[s][e][kk], kf[e][kk], acc, 0, 0, 0);
                #pragma unroll
                for (int r = 0; r < 4; ++r)
                    Ss[(s * 16 + 4 * lg + r) * SS_R + l16 * 20 + h0 + e] = (_Float16)acc[r];
            }
        }
        __syncthreads();
        #pragma unroll
        for (int ss = 0; ss < 4; ++ss) {
            const int strip = ss >> 1;
            if (strip == 0 && !actA) continue;
            const int sii = (ss & 1) * 8 + w;
            const int its = strip ? itB : itA;
            half4v sfrag = *(const half4v*)&Ss[(strip * 16 + sii) * SS_R + l16 * 20 + 4 * lg];
            f32x4 z = {0.f, 0.f, 0.f, 0.f};
            f32x4 m1 = __builtin_amdgcn_mfma_f32_16x16x16f16(wpre_f, sfrag, z, 0, 0, 0);
            if ((jt < its) || (l16 <= sii)) {
                #pragma unroll
                for (int r = 0; r < 4; ++r) lp[ss][r] += __expf(m1[r]);
            }
        }
        __syncthreads();
    }

    float lrec[4][4];
    #pragma unroll
    for (int ss = 0; ss < 4; ++ss)
        #pragma unroll
        for (int r = 0; r < 4; ++r) {
            float val = lp[ss][r];
            val += __shfl_xor(val, 1, 64);
            val += __shfl_xor(val, 2, 64);
            val += __shfl_xor(val, 4, 64);
            val += __shfl_xor(val, 8, 64);
            lrec[ss][r] = 1.0f / val;
        }

    f32x4 oacc[2][2][4];
    #pragma unroll
    for (int s = 0; s < 2; ++s)
        #pragma unroll
        for (int e = 0; e < 2; ++e)
            #pragma unroll
            for (int ds = 0; ds < 4; ++ds)
                oacc[s][e][ds] = (f32x4){0.f, 0.f, 0.f, 0.f};

    for (int jt = 0; jt <= itB; ++jt) {
        const int j0 = jt * 16;
        const bool actA = (jt <= itA);
        half4v kf[2][4];
        #pragma unroll
        for (int e = 0; e < 2; ++e) {
            const float* krow = k + ((bh0 + h0 + e) * N_ + j0 + l16) * D_ + 4 * lg;
            #pragma unroll
            for (int kk = 0; kk < 4; ++kk) kf[e][kk] = cvt4(*(const f32x4*)(krow + kk * 16));
        }
        half4v vf[2][4];
        #pragma unroll
        for (int e = 0; e < 2; ++e)
            #pragma unroll
            for (int ds = 0; ds < 4; ++ds) {
                f32x4 vv;
                #pragma unroll
                for (int xx = 0; xx < 4; ++xx)
                    vv[xx] = v[((bh0 + h0 + e) * N_ + j0 + 4 * lg + xx) * D_ + ds * 16 + l16];
                vf[e][ds] = cvt4(vv);
            }
        #pragma unroll
        for (int s = 0; s < 2; ++s) {
            if (s == 0 && !actA) continue;
            #pragma unroll
            for (int e = 0; e < 2; ++e) {
                f32x4 acc = {0.f, 0.f, 0.f, 0.f};
                #pragma unroll
                for (int kk = 0; kk < 4; ++kk)
                    acc = __builtin_amdgcn_mfma_f32_16x16x16f16(qf[s][e][kk], kf[e][kk], acc, 0, 0, 0);
                #pragma unroll
                for (int r = 0; r < 4; ++r)
                    Ss[(s * 16 + 4 * lg + r) * SS_R + l16 * 20 + h0 + e] = (_Float16)acc[r];
            }
        }
        __syncthreads();
        #pragma unroll
        for (int ss = 0; ss < 4; ++ss) {
            const int strip = ss >> 1;
            if (strip == 0 && !actA) continue;
            const int sii = (ss & 1) * 8 + w;
            const int its = strip ? itB : itA;
            half4v sfrag = *(const half4v*)&Ss[(strip * 16 + sii) * SS_R + l16 * 20 + 4 * lg];
            f32x4 z = {0.f, 0.f, 0.f, 0.f};
            f32x4 m1 = __builtin_amdgcn_mfma_f32_16x16x16f16(wpre_f, sfrag, z, 0, 0, 0);
            const bool ok = (jt < its) || (l16 <= sii);
            half4v pfrag;
            #pragma unroll
            for (int r = 0; r < 4; ++r)
                pfrag[r] = (_Float16)(ok ? __expf(m1[r]) * lrec[ss][r] : 0.f);
            f32x4 m2 = __builtin_amdgcn_mfma_f32_16x16x16f16(wpost_f, pfrag, z, 0, 0, 0);
            #pragma unroll
            for (int r = 0; r < 4; ++r)
                A2s[(4 * lg + r) * 648 + (strip * 16 + sii) * 20 + l16] = (_Float16)m2[r];
        }
        __syncthreads();
        #pragma unroll
        for (int s = 0; s < 2; ++s) {
            if (s == 0 && !actA) continue;
            #pragma unroll
            for (int e = 0; e < 2; ++e) {
                half4v bfrag = *(const half4v*)&A2s[(h0 + e) * 648 + (s * 16 + l16) * 20 + 4 * lg];
                #pragma unroll
                for (int ds = 0; ds < 4; ++ds)
                    oacc[s][e][ds] = __builtin_amdgcn_mfma_f32_16x16x16f16(vf[e][ds], bfrag, oacc[s][e][ds], 0, 0, 0);
            }
        }
    }

    #pragma unroll
    for (int s = 0; s < 2; ++s) {
        const int i0s = s ? i0B : i0A;
        #pragma unroll
        for (int e = 0; e < 2; ++e) {
            float* orow = out + ((bh0 + h0 + e) * N_ + i0s + l16) * D_;
            #pragma unroll
            for (int ds = 0; ds < 4; ++ds)
                *(f32x4*)&orow[ds * 16 + 4 * lg] = oacc[s][e][ds];
        }
    }
}

extern "C" void kernel_launch(void* const* d_in, const int* in_sizes, int n_in,
                              void* d_out, int out_size, void* d_ws, size_t ws_size,
                              hipStream_t stream) {
    const float* q     = (const float*)d_in[0];
    const float* k     = (const float*)d_in[1];
    const float* v     = (const float*)d_in[2];
    const float* Wpre  = (const float*)d_in[3];
    const float* Wpost = (const float*)d_in[4];
    float* out = (float*)d_out;
    _Float16* VT   = (_Float16*)((char*)d_ws + VT_OFF);
    float*    lbuf = (float*)((char*)d_ws + LB_OFF);
    _Float16* Ebuf = (_Float16*)((char*)d_ws + E_OFF);

    if (ws_size >= WS_NEED) {
        prep_vt<<<dim3(B_ * H_ * (N_ / 64)), dim3(256), 0, stream>>>(v, VT);
        hipMemsetAsync((char*)d_ws + LB_OFF, 0, LB_SZ, stream);
        attend_sweep1<<<dim3(512), dim3(512), 0, stream>>>(q, k, Wpre, lbuf, Ebuf);
        attend_sweep2<<<dim3(512), dim3(512), 0, stream>>>(Ebuf, VT, Wpost, lbuf, out);
    } else {
        attend_fused<<<dim3(B_ * 32), dim3(512), 0, stream>>>(q, k, v, Wpre, Wpost, out);
    }
}